// Round 1
// baseline (762.737 us; speedup 1.0000x reference)
//
#include <hip/hip_runtime.h>

// ---------------------------------------------------------------------------
// BlockGNN on MI355X, round 3: fused aggregate+GEMM.
//   - u_j = s_j * (h_j + res_j) stored bf16
//   - per 64-row block: gather-aggregate rows directly into LDS A-tile,
//     then MFMA GEMM vs W (staged per 32-k chunk), fused epilogue.
//   - removes the aggA global round-trip and overlaps gather with MFMA
//     across blocks.
// ---------------------------------------------------------------------------

typedef __bf16 bf16x8 __attribute__((ext_vector_type(8)));
typedef float f32x4 __attribute__((ext_vector_type(4)));

__device__ inline float bf2f(unsigned short u) {
  union { unsigned int i; float f; } v;
  v.i = (unsigned int)u << 16;
  return v.f;
}
__device__ inline unsigned short f2bf(float f) {
  union { unsigned int i; float f; } v;
  v.f = f;
  unsigned int i = v.i;
  return (unsigned short)((i + 0x7fffu + ((i >> 16) & 1u)) >> 16);  // RNE
}
__device__ inline unsigned int pack2(float a, float b) {
  return (unsigned int)f2bf(a) | ((unsigned int)f2bf(b) << 16);
}
__device__ inline void acc8(float* acc, uint4 r) {
  unsigned int w[4] = {r.x, r.y, r.z, r.w};
#pragma unroll
  for (int q = 0; q < 4; ++q) {
    acc[2 * q] += bf2f((unsigned short)(w[q] & 0xffffu));
    acc[2 * q + 1] += bf2f((unsigned short)(w[q] >> 16));
  }
}

// ----------------------------- CSR build -----------------------------------

__global__ void count_deg_kernel(const int* __restrict__ dst, int* __restrict__ deg, int E) {
  int e = blockIdx.x * blockDim.x + threadIdx.x;
  if (e < E) atomicAdd(&deg[dst[e]], 1);
}

__global__ void inv_s_kernel(const int* __restrict__ deg, float* __restrict__ inv_s, int N) {
  int i = blockIdx.x * blockDim.x + threadIdx.x;
  if (i < N) inv_s[i] = rsqrtf((float)(deg[i] + 1));  // +1 self loop
}

__global__ void scan_partial_kernel(const int* __restrict__ deg, int* __restrict__ bsum, int N) {
  __shared__ int s[256];
  int i = blockIdx.x * 256 + threadIdx.x;
  s[threadIdx.x] = (i < N) ? deg[i] : 0;
  __syncthreads();
  for (int off = 128; off > 0; off >>= 1) {
    if (threadIdx.x < off) s[threadIdx.x] += s[threadIdx.x + off];
    __syncthreads();
  }
  if (threadIdx.x == 0) bsum[blockIdx.x] = s[0];
}

__global__ void scan_block_kernel(const int* __restrict__ bsum, int* __restrict__ boff,
                                  int* __restrict__ row_off, int NB, int N) {
  __shared__ int s[256];
  int v = (threadIdx.x < NB) ? bsum[threadIdx.x] : 0;
  s[threadIdx.x] = v;
  __syncthreads();
  for (int off = 1; off < 256; off <<= 1) {
    int t = (threadIdx.x >= off) ? s[threadIdx.x - off] : 0;
    __syncthreads();
    s[threadIdx.x] += t;
    __syncthreads();
  }
  boff[threadIdx.x] = s[threadIdx.x] - v;
  if (threadIdx.x == 255) row_off[N] = s[255];
}

__global__ void scan_final_kernel(const int* __restrict__ deg, const int* __restrict__ boff,
                                  int* __restrict__ row_off, int N) {
  __shared__ int s[256];
  int i = blockIdx.x * 256 + threadIdx.x;
  int v = (i < N) ? deg[i] : 0;
  s[threadIdx.x] = v;
  __syncthreads();
  for (int off = 1; off < 256; off <<= 1) {
    int t = (threadIdx.x >= off) ? s[threadIdx.x - off] : 0;
    __syncthreads();
    s[threadIdx.x] += t;
    __syncthreads();
  }
  if (i < N) row_off[i] = boff[blockIdx.x] + s[threadIdx.x] - v;
}

__global__ void fill_csr_kernel(const int* __restrict__ src, const int* __restrict__ dst,
                                const int* __restrict__ row_off, int* __restrict__ cursor,
                                int* __restrict__ col, int E) {
  int e = blockIdx.x * blockDim.x + threadIdx.x;
  if (e < E) {
    int d = dst[e];
    int pos = atomicAdd(&cursor[d], 1);
    col[row_off[d] + pos] = src[e];
  }
}

// ----------------------------- prep ----------------------------------------

// u_x[i][c] = bf16( inv_s[i] * x[i][c] ),  CH = 128
__global__ void prep_ux_kernel(const float* __restrict__ x, const float* __restrict__ inv_s,
                               unsigned short* __restrict__ u, int total) {
  int idx = blockIdx.x * 256 + threadIdx.x;
  if (idx < total) {
    int i = idx >> 7;
    u[idx] = f2bf(inv_s[i] * x[idx]);
  }
}

// Wt[n][k] = bf16( W[k][n] );  W is [K][Ncol] row-major
__global__ void transpose_w_kernel(const float* __restrict__ W, unsigned short* __restrict__ Wt,
                                   int K, int Ncol) {
  int idx = blockIdx.x * 256 + threadIdx.x;
  if (idx < K * Ncol) {
    int k = idx / Ncol, n = idx - k * Ncol;
    Wt[n * K + k] = f2bf(W[idx]);
  }
}

// ----------------------- fused aggregate + GEMM ------------------------------
// Per block: 64 dst rows.
//   Phase 1: each wave aggregates 16 rows:  a_i = s_i*(u_i + sum_j u_j) -> As (LDS, bf16)
//   Phase 2: C[64,256] = As @ W  (+bias, opt relu)
//   WRITE_U: out = bf16( inv_s[r] * (C + gh[batch[r]]) )   (next layer's u)
//   else:    out = bf16( C )                               (final h)
template <int K, bool RELU, bool WRITE_U>
__global__ __launch_bounds__(256) void fused_agg_gemm_kernel(
    const unsigned short* __restrict__ u,   // [M][K] bf16 (pre-scaled features)
    const int* __restrict__ row_off, const int* __restrict__ col,
    const float* __restrict__ inv_s,
    const unsigned short* __restrict__ Bt,  // [256][K] bf16 (W transposed)
    const float* __restrict__ bias,         // [256]
    const int* __restrict__ batch, const float* __restrict__ gh,  // [G][256]
    unsigned short* __restrict__ out,       // [M][256] bf16
    int M) {
  constexpr int BK = 32;
  constexpr int LDTA = K + 8;  // ushorts; rows 16B-aligned, ds_read 2-way (free)
  constexpr int LDTB = 40;     // 80 B rows, 2-way (free)
  __shared__ unsigned short As[64 * LDTA];
  __shared__ unsigned short Bs[256 * LDTB];
  int tid = threadIdx.x;
  int wave = tid >> 6, lane = tid & 63;
  int quad = lane >> 4, l15 = lane & 15;
  int row0 = blockIdx.x * 64;

  // ---------------- phase 1: gather-aggregate into As ----------------
  constexpr int LPR = K / 8;    // lanes per row (16B each)
  constexpr int EPW = 64 / LPR; // edges in parallel per wave
  {
    int sub = lane / LPR;
    int c = lane % LPR;
    for (int rr = 0; rr < 16; ++rr) {
      int r = wave * 16 + rr;
      int i = row0 + r;
      if (i >= M) break;  // wave-uniform; no sync inside this loop
      int e0 = row_off[i], e1 = row_off[i + 1];
      float acc[8] = {};
      int e = e0 + sub;
      // 4 edges in flight per lane-group (64 B/lane outstanding)
      for (; e + 3 * EPW < e1; e += 4 * EPW) {
        int j0 = col[e];
        int j1 = col[e + EPW];
        int j2 = col[e + 2 * EPW];
        int j3 = col[e + 3 * EPW];
        uint4 r0 = *(const uint4*)&u[(size_t)j0 * K + c * 8];
        uint4 r1 = *(const uint4*)&u[(size_t)j1 * K + c * 8];
        uint4 r2 = *(const uint4*)&u[(size_t)j2 * K + c * 8];
        uint4 r3 = *(const uint4*)&u[(size_t)j3 * K + c * 8];
        acc8(acc, r0);
        acc8(acc, r1);
        acc8(acc, r2);
        acc8(acc, r3);
      }
      for (; e < e1; e += EPW) {
        int j = col[e];
        uint4 r4 = *(const uint4*)&u[(size_t)j * K + c * 8];
        acc8(acc, r4);
      }
#pragma unroll
      for (int k = 0; k < 8; ++k) {
        acc[k] += __shfl_down(acc[k], 32);
        if (EPW == 4) acc[k] += __shfl_down(acc[k], 16);
      }
      if (lane < LPR) {
        uint4 self = *(const uint4*)&u[(size_t)i * K + c * 8];
        acc8(acc, self);
        float s = inv_s[i];
        uint4 o;
        o.x = pack2(s * acc[0], s * acc[1]);
        o.y = pack2(s * acc[2], s * acc[3]);
        o.z = pack2(s * acc[4], s * acc[5]);
        o.w = pack2(s * acc[6], s * acc[7]);
        *(uint4*)&As[r * LDTA + c * 8] = o;
      }
    }
  }
  // NOTE: no explicit barrier here — the first in-loop __syncthreads() below
  // orders all As writes before any As read.

  // ---------------- phase 2: MFMA GEMM ----------------
  f32x4 acc2[4][4];
#pragma unroll
  for (int m = 0; m < 4; ++m)
#pragma unroll
    for (int n = 0; n < 4; ++n) acc2[m][n] = (f32x4){0.f, 0.f, 0.f, 0.f};

  for (int k0 = 0; k0 < K; k0 += BK) {
#pragma unroll
    for (int p = 0; p < 4; ++p) {  // stage B: 256 rows x 32 k
      int n = (tid >> 2) + p * 64, kq = tid & 3;
      *(uint4*)&Bs[n * LDTB + kq * 8] = *(const uint4*)&Bt[(size_t)n * K + k0 + kq * 8];
    }
    __syncthreads();
    bf16x8 af[4], bfr[4];
#pragma unroll
    for (int m = 0; m < 4; ++m)
      af[m] = __builtin_bit_cast(bf16x8,
                                 *(const uint4*)&As[(m * 16 + l15) * LDTA + k0 + quad * 8]);
#pragma unroll
    for (int n = 0; n < 4; ++n)
      bfr[n] = __builtin_bit_cast(
          bf16x8, *(const uint4*)&Bs[(wave * 64 + n * 16 + l15) * LDTB + quad * 8]);
#pragma unroll
    for (int m = 0; m < 4; ++m)
#pragma unroll
      for (int n = 0; n < 4; ++n)
        acc2[m][n] = __builtin_amdgcn_mfma_f32_16x16x32_bf16(af[m], bfr[n], acc2[m][n], 0, 0, 0);
    __syncthreads();
  }

  // epilogue: C/D map col=lane&15, row=(lane>>4)*4+reg
#pragma unroll
  for (int m = 0; m < 4; ++m) {
#pragma unroll
    for (int r = 0; r < 4; ++r) {
      int gr = row0 + m * 16 + quad * 4 + r;
      if (gr >= M) continue;
      float sv = 1.0f;
      int bofs = 0;
      if (WRITE_U) {
        sv = inv_s[gr];
        bofs = batch[gr] * 256;
      }
#pragma unroll
      for (int n = 0; n < 4; ++n) {
        int cc = wave * 64 + n * 16 + l15;
        float v = acc2[m][n][r] + bias[cc];
        if (RELU) v = fmaxf(v, 0.f);
        if (WRITE_U) v = sv * (v + gh[bofs + cc]);
        out[(size_t)gr * 256 + cc] = f2bf(v);
      }
    }
  }
}

// ----------------------------- pool + final ---------------------------------

__global__ void pool_kernel(const unsigned short* __restrict__ h, const int* __restrict__ batch,
                            float* __restrict__ gmsum, float* __restrict__ cnt, int N, int chunk) {
  int start = blockIdx.x * chunk;
  int end = min(start + chunk, N);
  if (start >= end) return;
  int c = threadIdx.x;
  int g = batch[start];
  float acc = 0.0f;
  int run = 0;
  for (int n = start; n < end; ++n) {
    int bg = batch[n];
    if (bg != g) {
      atomicAdd(&gmsum[g * 256 + c], acc);
      if (c == 0) atomicAdd(&cnt[g], (float)run);
      acc = 0.0f;
      run = 0;
      g = bg;
    }
    acc += bf2f(h[(size_t)n * 256 + c]);
    run++;
  }
  atomicAdd(&gmsum[g * 256 + c], acc);
  if (c == 0) atomicAdd(&cnt[g], (float)run);
}

__global__ void final_kernel(const float* __restrict__ gmsum, const float* __restrict__ cnt,
                             const float* __restrict__ gh, const float* __restrict__ Wlin,
                             const float* __restrict__ blin, float* __restrict__ y,
                             float* __restrict__ gm_out, int G) {
  int g = blockIdx.x;
  int c = threadIdx.x;
  __shared__ float row[256];
  float v = gmsum[g * 256 + c] / fmaxf(cnt[g], 1.0f) + gh[g * 256 + c];
  gm_out[g * 256 + c] = v;
  row[c] = v;
  __syncthreads();
  if (c < 10) {
    float acc = blin[c];
    for (int k = 0; k < 256; ++k) acc += row[k] * Wlin[k * 10 + c];
    y[g * 10 + c] = acc;
  }
}

// ----------------------------- launch ----------------------------------------

extern "C" void kernel_launch(void* const* d_in, const int* in_sizes, int n_in,
                              void* d_out, int out_size, void* d_ws, size_t ws_size,
                              hipStream_t stream) {
  const float* x = (const float*)d_in[0];
  const int* ei = (const int*)d_in[1];
  const int* batch = (const int*)d_in[2];
  const float* gh = (const float*)d_in[3];
  const float* W0 = (const float*)d_in[4];
  const float* b0 = (const float*)d_in[5];
  const float* Ws = (const float*)d_in[6];
  const float* bs = (const float*)d_in[7];
  const float* Wlin = (const float*)d_in[8];
  const float* blin = (const float*)d_in[9];
  float* out = (float*)d_out;

  const int N = in_sizes[2];
  const int E = in_sizes[1] / 2;
  const int G = in_sizes[3] / 256;
  const int H = 256, L = 3, C = 10, F = 128;

  char* ws = (char*)d_ws;
  size_t off = 0;
  auto alloc = [&](size_t bytes) {
    void* p = ws + off;
    off += (bytes + 255) & ~(size_t)255;
    return p;
  };
  int* deg = (int*)alloc((size_t)N * 4);
  int* cursor = (int*)alloc((size_t)N * 4);
  int* row_off = (int*)alloc((size_t)(N + 1) * 4);
  int* bsum = (int*)alloc(256 * 4);
  int* boff = (int*)alloc(256 * 4);
  int* col = (int*)alloc((size_t)E * 4);
  float* inv_s = (float*)alloc((size_t)N * 4);
  float* cnt = (float*)alloc((size_t)G * 4);
  float* gmsum = (float*)alloc((size_t)G * H * 4);
  unsigned short* u_x = (unsigned short*)alloc((size_t)N * F * 2);   // s*x
  unsigned short* uA = (unsigned short*)alloc((size_t)N * H * 2);    // s*(h+res)
  unsigned short* hfin = (unsigned short*)alloc((size_t)N * H * 2);  // final h
  unsigned short* Wt0 = (unsigned short*)alloc((size_t)F * H * 2);   // [256][128]
  unsigned short* WtS = (unsigned short*)alloc((size_t)L * H * H * 2);

  const int* srcv = ei;
  const int* dstv = ei + E;

  hipMemsetAsync(deg, 0, (size_t)N * 4, stream);
  hipMemsetAsync(cursor, 0, (size_t)N * 4, stream);
  hipMemsetAsync(cnt, 0, (size_t)G * 4, stream);
  hipMemsetAsync(gmsum, 0, (size_t)G * H * 4, stream);

  int EB = (E + 255) / 256;
  int NB = (N + 255) / 256;
  count_deg_kernel<<<EB, 256, 0, stream>>>(dstv, deg, E);
  inv_s_kernel<<<NB, 256, 0, stream>>>(deg, inv_s, N);
  scan_partial_kernel<<<NB, 256, 0, stream>>>(deg, bsum, N);
  scan_block_kernel<<<1, 256, 0, stream>>>(bsum, boff, row_off, NB, N);
  scan_final_kernel<<<NB, 256, 0, stream>>>(deg, boff, row_off, N);
  fill_csr_kernel<<<EB, 256, 0, stream>>>(srcv, dstv, row_off, cursor, col, E);

  prep_ux_kernel<<<(N * F + 255) / 256, 256, 0, stream>>>(x, inv_s, u_x, N * F);
  transpose_w_kernel<<<(F * H + 255) / 256, 256, 0, stream>>>(W0, Wt0, F, H);
  for (int l = 0; l < L; ++l)
    transpose_w_kernel<<<(H * H + 255) / 256, 256, 0, stream>>>(Ws + (size_t)l * H * H,
                                                                WtS + (size_t)l * H * H, H, H);

  int GRID = (N + 63) / 64;

  // layer 0: fused agg(u_x) + GEMM K=128 (no relu) -> uA = s*(h0+res)
  fused_agg_gemm_kernel<128, false, true><<<GRID, 256, 0, stream>>>(
      u_x, row_off, col, inv_s, Wt0, b0, batch, gh, uA, N);
  // layers 1..2: fused agg(uA) + GEMM relu -> uA
  for (int l = 0; l < 2; ++l)
    fused_agg_gemm_kernel<256, true, true><<<GRID, 256, 0, stream>>>(
        uA, row_off, col, inv_s, WtS + (size_t)l * H * H, bs + (size_t)l * H, batch, gh, uA, N);
  // layer 3: fused agg(uA) + GEMM relu -> h (bf16)
  fused_agg_gemm_kernel<256, true, false><<<GRID, 256, 0, stream>>>(
      uA, row_off, col, inv_s, WtS + (size_t)2 * H * H, bs + (size_t)2 * H, batch, gh, hfin, N);

  int chunk = (N + 255) / 256;
  pool_kernel<<<256, 256, 0, stream>>>(hfin, batch, gmsum, cnt, N, chunk);
  final_kernel<<<G, 256, 0, stream>>>(gmsum, cnt, gh, Wlin, blin, out, out + (size_t)G * C, G);
}

// Round 2
// 575.410 us; speedup vs baseline: 1.3256x; 1.3256x over previous
//
#include <hip/hip_runtime.h>

// ---------------------------------------------------------------------------
// BlockGNN on MI355X, round 4: split pipeline (round-2 structure) with a
// deep-pipelined aggregate kernel.
//   - u_j = s_j * (h_j + res_j) stored bf16 -> aggregation is a pure gather-sum
//   - aggregate: clamped 8-deep gather batch (128 B/lane in flight) to fix
//     the latency-bound gather identified in the fused-kernel post-mortem
//   - MFMA bf16 GEMM with fused bias/relu/residual/scale epilogue (unchanged)
// ---------------------------------------------------------------------------

typedef __bf16 bf16x8 __attribute__((ext_vector_type(8)));
typedef float f32x4 __attribute__((ext_vector_type(4)));

__device__ inline float bf2f(unsigned short u) {
  union { unsigned int i; float f; } v;
  v.i = (unsigned int)u << 16;
  return v.f;
}
__device__ inline unsigned short f2bf(float f) {
  union { unsigned int i; float f; } v;
  v.f = f;
  unsigned int i = v.i;
  return (unsigned short)((i + 0x7fffu + ((i >> 16) & 1u)) >> 16);  // RNE
}
__device__ inline unsigned int pack2(float a, float b) {
  return (unsigned int)f2bf(a) | ((unsigned int)f2bf(b) << 16);
}
__device__ inline void acc8(float* acc, uint4 r) {
  unsigned int w[4] = {r.x, r.y, r.z, r.w};
#pragma unroll
  for (int q = 0; q < 4; ++q) {
    acc[2 * q] += bf2f((unsigned short)(w[q] & 0xffffu));
    acc[2 * q + 1] += bf2f((unsigned short)(w[q] >> 16));
  }
}

// ----------------------------- CSR build -----------------------------------

__global__ void count_deg_kernel(const int* __restrict__ dst, int* __restrict__ deg, int E) {
  int e = blockIdx.x * blockDim.x + threadIdx.x;
  if (e < E) atomicAdd(&deg[dst[e]], 1);
}

__global__ void inv_s_kernel(const int* __restrict__ deg, float* __restrict__ inv_s, int N) {
  int i = blockIdx.x * blockDim.x + threadIdx.x;
  if (i < N) inv_s[i] = rsqrtf((float)(deg[i] + 1));  // +1 self loop
}

__global__ void scan_partial_kernel(const int* __restrict__ deg, int* __restrict__ bsum, int N) {
  __shared__ int s[256];
  int i = blockIdx.x * 256 + threadIdx.x;
  s[threadIdx.x] = (i < N) ? deg[i] : 0;
  __syncthreads();
  for (int off = 128; off > 0; off >>= 1) {
    if (threadIdx.x < off) s[threadIdx.x] += s[threadIdx.x + off];
    __syncthreads();
  }
  if (threadIdx.x == 0) bsum[blockIdx.x] = s[0];
}

__global__ void scan_block_kernel(const int* __restrict__ bsum, int* __restrict__ boff,
                                  int* __restrict__ row_off, int NB, int N) {
  __shared__ int s[256];
  int v = (threadIdx.x < NB) ? bsum[threadIdx.x] : 0;
  s[threadIdx.x] = v;
  __syncthreads();
  for (int off = 1; off < 256; off <<= 1) {
    int t = (threadIdx.x >= off) ? s[threadIdx.x - off] : 0;
    __syncthreads();
    s[threadIdx.x] += t;
    __syncthreads();
  }
  boff[threadIdx.x] = s[threadIdx.x] - v;
  if (threadIdx.x == 255) row_off[N] = s[255];
}

__global__ void scan_final_kernel(const int* __restrict__ deg, const int* __restrict__ boff,
                                  int* __restrict__ row_off, int N) {
  __shared__ int s[256];
  int i = blockIdx.x * 256 + threadIdx.x;
  int v = (i < N) ? deg[i] : 0;
  s[threadIdx.x] = v;
  __syncthreads();
  for (int off = 1; off < 256; off <<= 1) {
    int t = (threadIdx.x >= off) ? s[threadIdx.x - off] : 0;
    __syncthreads();
    s[threadIdx.x] += t;
    __syncthreads();
  }
  if (i < N) row_off[i] = boff[blockIdx.x] + s[threadIdx.x] - v;
}

__global__ void fill_csr_kernel(const int* __restrict__ src, const int* __restrict__ dst,
                                const int* __restrict__ row_off, int* __restrict__ cursor,
                                int* __restrict__ col, int E) {
  int e = blockIdx.x * blockDim.x + threadIdx.x;
  if (e < E) {
    int d = dst[e];
    int pos = atomicAdd(&cursor[d], 1);
    col[row_off[d] + pos] = src[e];
  }
}

// ----------------------------- prep ----------------------------------------

// u_x[i][c] = bf16( inv_s[i] * x[i][c] ),  CH = 128
__global__ void prep_ux_kernel(const float* __restrict__ x, const float* __restrict__ inv_s,
                               unsigned short* __restrict__ u, int total) {
  int idx = blockIdx.x * 256 + threadIdx.x;
  if (idx < total) {
    int i = idx >> 7;
    u[idx] = f2bf(inv_s[i] * x[idx]);
  }
}

// Wt[n][k] = bf16( W[k][n] );  W is [K][Ncol] row-major
__global__ void transpose_w_kernel(const float* __restrict__ W, unsigned short* __restrict__ Wt,
                                   int K, int Ncol) {
  int idx = blockIdx.x * 256 + threadIdx.x;
  if (idx < K * Ncol) {
    int k = idx / Ncol, n = idx - k * Ncol;
    Wt[n * K + k] = f2bf(W[idx]);
  }
}

// ----------------------------- aggregate ------------------------------------
// out_i = bf16( s_i * ( u_i + sum_{j in in(i)} u_j ) )
// One wave per node; LPR lanes (16B each) per row; EPW edge-groups per wave.
// Clamped 8-deep batch: 8 col loads, then 8 row-gathers in flight (128 B/lane),
// then predicated accumulate. Short rows still issue at full depth (clamp to
// the last edge + per-slot validity), so there is no serial tail ladder.
template <int CH>
__global__ __launch_bounds__(256) void aggregate_kernel(
    const unsigned short* __restrict__ u, const int* __restrict__ row_off,
    const int* __restrict__ col, const float* __restrict__ inv_s,
    unsigned short* __restrict__ out, int N) {
  constexpr int LPR = CH / 8;    // lanes per row (each lane: 8 bf16 = 16B)
  constexpr int EPW = 64 / LPR;  // edge-groups in parallel per wave
  int wave = threadIdx.x >> 6;
  int lane = threadIdx.x & 63;
  int i = blockIdx.x * 4 + wave;
  if (i >= N) return;
  int sub = lane / LPR;
  int c = lane % LPR;
  int e0 = row_off[i], e1 = row_off[i + 1];
  int last = e1 - 1;
  float acc[8] = {};
  for (int e = e0 + sub; e < e1; e += 8 * EPW) {
    int j[8];
    bool val[8];
#pragma unroll
    for (int q = 0; q < 8; ++q) {
      int ee = e + q * EPW;
      val[q] = ee < e1;
      j[q] = col[val[q] ? ee : last];
    }
    uint4 r[8];
#pragma unroll
    for (int q = 0; q < 8; ++q) r[q] = *(const uint4*)&u[(size_t)j[q] * CH + c * 8];
#pragma unroll
    for (int q = 0; q < 8; ++q)
      if (val[q]) acc8(acc, r[q]);
  }
#pragma unroll
  for (int k = 0; k < 8; ++k) {
    acc[k] += __shfl_down(acc[k], 32);
    if (EPW == 4) acc[k] += __shfl_down(acc[k], 16);
  }
  if (lane < LPR) {
    uint4 self = *(const uint4*)&u[(size_t)i * CH + c * 8];
    acc8(acc, self);
    float s = inv_s[i];
    uint4 o;
    o.x = pack2(s * acc[0], s * acc[1]);
    o.y = pack2(s * acc[2], s * acc[3]);
    o.z = pack2(s * acc[4], s * acc[5]);
    o.w = pack2(s * acc[6], s * acc[7]);
    *(uint4*)&out[(size_t)i * CH + c * 8] = o;
  }
}

// ----------------------------- MFMA GEMM ------------------------------------
// C[M,256] = A[M,K] @ W[K,256] (+bias, opt relu)
// WRITE_U: out = bf16( inv_s[r] * (C + gh[batch[r]]) )   (next layer's u)
// else:    out = bf16( C )                               (final h)
template <int K, bool RELU, bool WRITE_U>
__global__ __launch_bounds__(256) void gemm_kernel(
    const unsigned short* __restrict__ A,   // [M][K] bf16
    const unsigned short* __restrict__ Bt,  // [256][K] bf16 (W transposed)
    const float* __restrict__ bias,         // [256]
    const float* __restrict__ inv_s, const int* __restrict__ batch,
    const float* __restrict__ gh,           // [G][256]
    unsigned short* __restrict__ out,       // [M][256] bf16
    int M) {
  constexpr int BK = 32;
  constexpr int LDT = 40;  // padded stride in ushorts: 80 B (16B-aligned, bank-friendly)
  __shared__ unsigned short As[64 * LDT];
  __shared__ unsigned short Bs[256 * LDT];
  int tid = threadIdx.x;
  int wave = tid >> 6, lane = tid & 63;
  int quad = lane >> 4, l15 = lane & 15;
  int row0 = blockIdx.x * 64;
  f32x4 acc[4][4];
#pragma unroll
  for (int m = 0; m < 4; ++m)
#pragma unroll
    for (int n = 0; n < 4; ++n) acc[m][n] = (f32x4){0.f, 0.f, 0.f, 0.f};

  for (int k0 = 0; k0 < K; k0 += BK) {
    {  // stage A: 64 rows x 32 k
      int r = tid >> 2, kq = tid & 3;
      int gr = row0 + r;
      uint4 v = make_uint4(0u, 0u, 0u, 0u);
      if (gr < M) v = *(const uint4*)&A[(size_t)gr * K + k0 + kq * 8];
      *(uint4*)&As[r * LDT + kq * 8] = v;
    }
#pragma unroll
    for (int p = 0; p < 4; ++p) {  // stage B: 256 rows x 32 k
      int n = (tid >> 2) + p * 64, kq = tid & 3;
      *(uint4*)&Bs[n * LDT + kq * 8] = *(const uint4*)&Bt[(size_t)n * K + k0 + kq * 8];
    }
    __syncthreads();
    bf16x8 af[4], bfr[4];
#pragma unroll
    for (int m = 0; m < 4; ++m)
      af[m] = __builtin_bit_cast(bf16x8, *(const uint4*)&As[(m * 16 + l15) * LDT + quad * 8]);
#pragma unroll
    for (int n = 0; n < 4; ++n)
      bfr[n] = __builtin_bit_cast(bf16x8,
                                  *(const uint4*)&Bs[(wave * 64 + n * 16 + l15) * LDT + quad * 8]);
#pragma unroll
    for (int m = 0; m < 4; ++m)
#pragma unroll
      for (int n = 0; n < 4; ++n)
        acc[m][n] = __builtin_amdgcn_mfma_f32_16x16x32_bf16(af[m], bfr[n], acc[m][n], 0, 0, 0);
    __syncthreads();
  }
  // epilogue: C/D map col=lane&15, row=(lane>>4)*4+reg
#pragma unroll
  for (int m = 0; m < 4; ++m) {
#pragma unroll
    for (int r = 0; r < 4; ++r) {
      int gr = row0 + m * 16 + quad * 4 + r;
      if (gr >= M) continue;
      float sv = 1.0f;
      int bofs = 0;
      if (WRITE_U) {
        sv = inv_s[gr];
        bofs = batch[gr] * 256;
      }
#pragma unroll
      for (int n = 0; n < 4; ++n) {
        int cc = wave * 64 + n * 16 + l15;
        float v = acc[m][n][r] + bias[cc];
        if (RELU) v = fmaxf(v, 0.f);
        if (WRITE_U) v = sv * (v + gh[bofs + cc]);
        out[(size_t)gr * 256 + cc] = f2bf(v);
      }
    }
  }
}

// ----------------------------- pool + final ---------------------------------

__global__ void pool_kernel(const unsigned short* __restrict__ h, const int* __restrict__ batch,
                            float* __restrict__ gmsum, float* __restrict__ cnt, int N, int chunk) {
  int start = blockIdx.x * chunk;
  int end = min(start + chunk, N);
  if (start >= end) return;
  int c = threadIdx.x;
  int g = batch[start];
  float acc = 0.0f;
  int run = 0;
  for (int n = start; n < end; ++n) {
    int bg = batch[n];
    if (bg != g) {
      atomicAdd(&gmsum[g * 256 + c], acc);
      if (c == 0) atomicAdd(&cnt[g], (float)run);
      acc = 0.0f;
      run = 0;
      g = bg;
    }
    acc += bf2f(h[(size_t)n * 256 + c]);
    run++;
  }
  atomicAdd(&gmsum[g * 256 + c], acc);
  if (c == 0) atomicAdd(&cnt[g], (float)run);
}

__global__ void final_kernel(const float* __restrict__ gmsum, const float* __restrict__ cnt,
                             const float* __restrict__ gh, const float* __restrict__ Wlin,
                             const float* __restrict__ blin, float* __restrict__ y,
                             float* __restrict__ gm_out, int G) {
  int g = blockIdx.x;
  int c = threadIdx.x;
  __shared__ float row[256];
  float v = gmsum[g * 256 + c] / fmaxf(cnt[g], 1.0f) + gh[g * 256 + c];
  gm_out[g * 256 + c] = v;
  row[c] = v;
  __syncthreads();
  if (c < 10) {
    float acc = blin[c];
    for (int k = 0; k < 256; ++k) acc += row[k] * Wlin[k * 10 + c];
    y[g * 10 + c] = acc;
  }
}

// ----------------------------- launch ----------------------------------------

extern "C" void kernel_launch(void* const* d_in, const int* in_sizes, int n_in,
                              void* d_out, int out_size, void* d_ws, size_t ws_size,
                              hipStream_t stream) {
  const float* x = (const float*)d_in[0];
  const int* ei = (const int*)d_in[1];
  const int* batch = (const int*)d_in[2];
  const float* gh = (const float*)d_in[3];
  const float* W0 = (const float*)d_in[4];
  const float* b0 = (const float*)d_in[5];
  const float* Ws = (const float*)d_in[6];
  const float* bs = (const float*)d_in[7];
  const float* Wlin = (const float*)d_in[8];
  const float* blin = (const float*)d_in[9];
  float* out = (float*)d_out;

  const int N = in_sizes[2];
  const int E = in_sizes[1] / 2;
  const int G = in_sizes[3] / 256;
  const int H = 256, L = 3, C = 10, F = 128;

  char* ws = (char*)d_ws;
  size_t off = 0;
  auto alloc = [&](size_t bytes) {
    void* p = ws + off;
    off += (bytes + 255) & ~(size_t)255;
    return p;
  };
  int* deg = (int*)alloc((size_t)N * 4);
  int* cursor = (int*)alloc((size_t)N * 4);
  int* row_off = (int*)alloc((size_t)(N + 1) * 4);
  int* bsum = (int*)alloc(256 * 4);
  int* boff = (int*)alloc(256 * 4);
  int* col = (int*)alloc((size_t)E * 4);
  float* inv_s = (float*)alloc((size_t)N * 4);
  float* cnt = (float*)alloc((size_t)G * 4);
  float* gmsum = (float*)alloc((size_t)G * H * 4);
  unsigned short* u_x = (unsigned short*)alloc((size_t)N * F * 2);   // s*x
  unsigned short* uA = (unsigned short*)alloc((size_t)N * H * 2);    // s*(h+res)
  unsigned short* aggA = (unsigned short*)alloc((size_t)N * H * 2);  // aggregate out / GEMM A
  unsigned short* hfin = (unsigned short*)alloc((size_t)N * H * 2);  // final h
  unsigned short* Wt0 = (unsigned short*)alloc((size_t)F * H * 2);   // [256][128]
  unsigned short* WtS = (unsigned short*)alloc((size_t)L * H * H * 2);

  const int* srcv = ei;
  const int* dstv = ei + E;

  hipMemsetAsync(deg, 0, (size_t)N * 4, stream);
  hipMemsetAsync(cursor, 0, (size_t)N * 4, stream);
  hipMemsetAsync(cnt, 0, (size_t)G * 4, stream);
  hipMemsetAsync(gmsum, 0, (size_t)G * H * 4, stream);

  int EB = (E + 255) / 256;
  int NB = (N + 255) / 256;
  count_deg_kernel<<<EB, 256, 0, stream>>>(dstv, deg, E);
  inv_s_kernel<<<NB, 256, 0, stream>>>(deg, inv_s, N);
  scan_partial_kernel<<<NB, 256, 0, stream>>>(deg, bsum, N);
  scan_block_kernel<<<1, 256, 0, stream>>>(bsum, boff, row_off, NB, N);
  scan_final_kernel<<<NB, 256, 0, stream>>>(deg, boff, row_off, N);
  fill_csr_kernel<<<EB, 256, 0, stream>>>(srcv, dstv, row_off, cursor, col, E);

  prep_ux_kernel<<<(N * F + 255) / 256, 256, 0, stream>>>(x, inv_s, u_x, N * F);
  transpose_w_kernel<<<(F * H + 255) / 256, 256, 0, stream>>>(W0, Wt0, F, H);
  for (int l = 0; l < L; ++l)
    transpose_w_kernel<<<(H * H + 255) / 256, 256, 0, stream>>>(Ws + (size_t)l * H * H,
                                                                WtS + (size_t)l * H * H, H, H);

  int AGG_GRID = (N + 3) / 4;
  int GEMM_GRID = (N + 63) / 64;

  // layer 0: agg(u_x) -> GEMM K=128 (no relu) -> uA = s*(h0+res)
  aggregate_kernel<128><<<AGG_GRID, 256, 0, stream>>>(u_x, row_off, col, inv_s, aggA, N);
  gemm_kernel<128, false, true><<<GEMM_GRID, 256, 0, stream>>>(aggA, Wt0, b0, inv_s, batch, gh,
                                                               uA, N);
  // layers 1..2: agg(uA) -> GEMM relu -> uA
  for (int l = 0; l < 2; ++l) {
    aggregate_kernel<256><<<AGG_GRID, 256, 0, stream>>>(uA, row_off, col, inv_s, aggA, N);
    gemm_kernel<256, true, true><<<GEMM_GRID, 256, 0, stream>>>(
        aggA, WtS + (size_t)l * H * H, bs + (size_t)l * H, inv_s, batch, gh, uA, N);
  }
  // layer 3: agg(uA) -> GEMM relu -> h (bf16)
  aggregate_kernel<256><<<AGG_GRID, 256, 0, stream>>>(uA, row_off, col, inv_s, aggA, N);
  gemm_kernel<256, true, false><<<GEMM_GRID, 256, 0, stream>>>(
      aggA, WtS + (size_t)2 * H * H, bs + (size_t)2 * H, inv_s, batch, gh, hfin, N);

  int chunk = (N + 255) / 256;
  pool_kernel<<<256, 256, 0, stream>>>(hfin, batch, gmsum, cnt, N, chunk);
  final_kernel<<<G, 256, 0, stream>>>(gmsum, cnt, gh, Wlin, blin, out, out + (size_t)G * C, G);
}

// Round 3
// 513.715 us; speedup vs baseline: 1.4847x; 1.1201x over previous
//
#include <hip/hip_runtime.h>

// ---------------------------------------------------------------------------
// BlockGNN on MI355X, round 5:
//   - aggregate: true 8-deep gather batch (sched_barrier fence keeps all 8
//     loads in flight; 32-bit SADDR offsets keep VGPR ~64)
//   - GEMM: BM=128 / 8-wave / 512-thread tile (halves B-staging + barriers)
//   - launch-count reduction: fused inv_s, single transpose kernel, 2 memsets
// ---------------------------------------------------------------------------

typedef __bf16 bf16x8 __attribute__((ext_vector_type(8)));
typedef float f32x4 __attribute__((ext_vector_type(4)));

__device__ inline float bf2f(unsigned short u) {
  union { unsigned int i; float f; } v;
  v.i = (unsigned int)u << 16;
  return v.f;
}
__device__ inline unsigned short f2bf(float f) {
  union { unsigned int i; float f; } v;
  v.f = f;
  unsigned int i = v.i;
  return (unsigned short)((i + 0x7fffu + ((i >> 16) & 1u)) >> 16);  // RNE
}
__device__ inline unsigned int pack2(float a, float b) {
  return (unsigned int)f2bf(a) | ((unsigned int)f2bf(b) << 16);
}
__device__ inline void acc8(float* acc, uint4 r) {
  unsigned int w[4] = {r.x, r.y, r.z, r.w};
#pragma unroll
  for (int q = 0; q < 4; ++q) {
    acc[2 * q] += bf2f((unsigned short)(w[q] & 0xffffu));
    acc[2 * q + 1] += bf2f((unsigned short)(w[q] >> 16));
  }
}

// ----------------------------- CSR build -----------------------------------

__global__ void count_deg_kernel(const int* __restrict__ dst, int* __restrict__ deg, int E) {
  int e = blockIdx.x * blockDim.x + threadIdx.x;
  if (e < E) atomicAdd(&deg[dst[e]], 1);
}

// fused: per-block degree sums for the scan + inv_s = rsqrt(deg+1)
__global__ void scan_partial_kernel(const int* __restrict__ deg, float* __restrict__ inv_s,
                                    int* __restrict__ bsum, int N) {
  __shared__ int s[256];
  int i = blockIdx.x * 256 + threadIdx.x;
  int d = (i < N) ? deg[i] : 0;
  if (i < N) inv_s[i] = rsqrtf((float)(d + 1));  // +1 self loop
  s[threadIdx.x] = d;
  __syncthreads();
  for (int off = 128; off > 0; off >>= 1) {
    if (threadIdx.x < off) s[threadIdx.x] += s[threadIdx.x + off];
    __syncthreads();
  }
  if (threadIdx.x == 0) bsum[blockIdx.x] = s[0];
}

__global__ void scan_block_kernel(const int* __restrict__ bsum, int* __restrict__ boff,
                                  int* __restrict__ row_off, int NB, int N) {
  __shared__ int s[256];
  int v = (threadIdx.x < NB) ? bsum[threadIdx.x] : 0;
  s[threadIdx.x] = v;
  __syncthreads();
  for (int off = 1; off < 256; off <<= 1) {
    int t = (threadIdx.x >= off) ? s[threadIdx.x - off] : 0;
    __syncthreads();
    s[threadIdx.x] += t;
    __syncthreads();
  }
  boff[threadIdx.x] = s[threadIdx.x] - v;
  if (threadIdx.x == 255) row_off[N] = s[255];
}

__global__ void scan_final_kernel(const int* __restrict__ deg, const int* __restrict__ boff,
                                  int* __restrict__ row_off, int N) {
  __shared__ int s[256];
  int i = blockIdx.x * 256 + threadIdx.x;
  int v = (i < N) ? deg[i] : 0;
  s[threadIdx.x] = v;
  __syncthreads();
  for (int off = 1; off < 256; off <<= 1) {
    int t = (threadIdx.x >= off) ? s[threadIdx.x - off] : 0;
    __syncthreads();
    s[threadIdx.x] += t;
    __syncthreads();
  }
  if (i < N) row_off[i] = boff[blockIdx.x] + s[threadIdx.x] - v;
}

__global__ void fill_csr_kernel(const int* __restrict__ src, const int* __restrict__ dst,
                                const int* __restrict__ row_off, int* __restrict__ cursor,
                                int* __restrict__ col, int E) {
  int e = blockIdx.x * blockDim.x + threadIdx.x;
  if (e < E) {
    int d = dst[e];
    int pos = atomicAdd(&cursor[d], 1);
    col[row_off[d] + pos] = src[e];
  }
}

// ----------------------------- prep ----------------------------------------

// u_x[i][c] = bf16( inv_s[i] * x[i][c] ),  CH = 128
__global__ void prep_ux_kernel(const float* __restrict__ x, const float* __restrict__ inv_s,
                               unsigned short* __restrict__ u, int total) {
  int idx = blockIdx.x * 256 + threadIdx.x;
  if (idx < total) {
    int i = idx >> 7;
    u[idx] = f2bf(inv_s[i] * x[idx]);
  }
}

// single kernel transposing W0 [128][256] and 3x Ws [256][256] to bf16
__global__ void transpose_all_kernel(const float* __restrict__ W0, const float* __restrict__ Ws,
                                     unsigned short* __restrict__ Wt0,
                                     unsigned short* __restrict__ WtS) {
  const int FH = 128 * 256, HH = 256 * 256;
  int idx = blockIdx.x * 256 + threadIdx.x;
  if (idx < FH) {
    int k = idx >> 8, n = idx & 255;
    Wt0[n * 128 + k] = f2bf(W0[idx]);
  } else {
    int t = idx - FH;
    if (t < 3 * HH) {
      int l = t >> 16;
      int rem = t & 65535;
      int k = rem >> 8, n = rem & 255;
      WtS[l * HH + n * 256 + k] = f2bf(Ws[t]);
    }
  }
}

// ----------------------------- aggregate ------------------------------------
// out_i = bf16( s_i * ( u_i + sum_{j in in(i)} u_j ) )
// One wave per node; LPR lanes (16B each) per row; EPW edge-groups per wave.
// 8-deep clamped gather batch; sched_barrier(0) pins all 8 loads before any
// accumulate so the compiler can't sink acc8 next to its load (round-4 binary
// had VGPR=32 => real depth ~2). 32-bit offsets keep addressing at 1 VGPR.
template <int CH>
__global__ __launch_bounds__(256) void aggregate_kernel(
    const unsigned short* __restrict__ u, const int* __restrict__ row_off,
    const int* __restrict__ col, const float* __restrict__ inv_s,
    unsigned short* __restrict__ out, int N) {
  constexpr int LPR = CH / 8;    // lanes per row (each lane: 8 bf16 = 16B)
  constexpr int EPW = 64 / LPR;  // edge-groups in parallel per wave
  int wave = threadIdx.x >> 6;
  int lane = threadIdx.x & 63;
  int i = blockIdx.x * 4 + wave;
  if (i >= N) return;
  int sub = lane / LPR;
  int c = lane % LPR;
  int e0 = row_off[i], e1 = row_off[i + 1];
  int last = e1 - 1;
  const char* u8 = (const char*)u;
  float acc[8] = {};
  for (int e = e0 + sub; e < e1; e += 8 * EPW) {
    unsigned off[8];
    bool val[8];
#pragma unroll
    for (int q = 0; q < 8; ++q) {
      int ee = e + q * EPW;
      val[q] = ee < e1;
      int j = col[val[q] ? ee : last];
      off[q] = (unsigned)j * (CH * 2) + c * 16;
    }
    uint4 r[8];
#pragma unroll
    for (int q = 0; q < 8; ++q) r[q] = *(const uint4*)(u8 + off[q]);
    __builtin_amdgcn_sched_barrier(0);  // keep all 8 gathers in flight
#pragma unroll
    for (int q = 0; q < 8; ++q)
      if (val[q]) acc8(acc, r[q]);
  }
#pragma unroll
  for (int k = 0; k < 8; ++k) {
    acc[k] += __shfl_down(acc[k], 32);
    if (EPW == 4) acc[k] += __shfl_down(acc[k], 16);
  }
  if (lane < LPR) {
    uint4 self = *(const uint4*)&u[(size_t)i * CH + c * 8];
    acc8(acc, self);
    float s = inv_s[i];
    uint4 o;
    o.x = pack2(s * acc[0], s * acc[1]);
    o.y = pack2(s * acc[2], s * acc[3]);
    o.z = pack2(s * acc[4], s * acc[5]);
    o.w = pack2(s * acc[6], s * acc[7]);
    *(uint4*)&out[(size_t)i * CH + c * 8] = o;
  }
}

// ----------------------------- MFMA GEMM ------------------------------------
// C[M,256] = A[M,K] @ W[K,256] (+bias, opt relu)
// BM=128, 8 waves (2 row-halves x 4 col-quarters), 512 threads.
// WRITE_U: out = bf16( inv_s[r] * (C + gh[batch[r]]) )   (next layer's u)
// else:    out = bf16( C )                               (final h)
template <int K, bool RELU, bool WRITE_U>
__global__ __launch_bounds__(512) void gemm_kernel(
    const unsigned short* __restrict__ A,   // [M][K] bf16
    const unsigned short* __restrict__ Bt,  // [256][K] bf16 (W transposed)
    const float* __restrict__ bias,         // [256]
    const float* __restrict__ inv_s, const int* __restrict__ batch,
    const float* __restrict__ gh,           // [G][256]
    unsigned short* __restrict__ out,       // [M][256] bf16
    int M) {
  constexpr int BK = 32;
  constexpr int LDT = 40;  // padded stride in ushorts: 80 B (16B-aligned, bank-friendly)
  __shared__ unsigned short As[128 * LDT];
  __shared__ unsigned short Bs[256 * LDT];
  int tid = threadIdx.x;
  int wave = tid >> 6, lane = tid & 63;
  int quad = lane >> 4, l15 = lane & 15;
  int wr = wave >> 2, wc = wave & 3;
  int row0 = blockIdx.x * 128;
  f32x4 acc[4][4];
#pragma unroll
  for (int m = 0; m < 4; ++m)
#pragma unroll
    for (int n = 0; n < 4; ++n) acc[m][n] = (f32x4){0.f, 0.f, 0.f, 0.f};

  for (int k0 = 0; k0 < K; k0 += BK) {
    {  // stage A: 128 rows x 32 k (one uint4 per thread)
      int r = tid >> 2, kq = tid & 3;
      int gr = row0 + r;
      uint4 v = make_uint4(0u, 0u, 0u, 0u);
      if (gr < M) v = *(const uint4*)&A[(size_t)gr * K + k0 + kq * 8];
      *(uint4*)&As[r * LDT + kq * 8] = v;
    }
#pragma unroll
    for (int p = 0; p < 2; ++p) {  // stage B: 256 rows x 32 k (two uint4 per thread)
      int n = (tid >> 2) + p * 128, kq = tid & 3;
      *(uint4*)&Bs[n * LDT + kq * 8] = *(const uint4*)&Bt[(size_t)n * K + k0 + kq * 8];
    }
    __syncthreads();
    bf16x8 af[4], bfr[4];
#pragma unroll
    for (int m = 0; m < 4; ++m)
      af[m] = __builtin_bit_cast(
          bf16x8, *(const uint4*)&As[(wr * 64 + m * 16 + l15) * LDT + quad * 8]);
#pragma unroll
    for (int n = 0; n < 4; ++n)
      bfr[n] = __builtin_bit_cast(
          bf16x8, *(const uint4*)&Bs[(wc * 64 + n * 16 + l15) * LDT + quad * 8]);
#pragma unroll
    for (int m = 0; m < 4; ++m)
#pragma unroll
      for (int n = 0; n < 4; ++n)
        acc[m][n] = __builtin_amdgcn_mfma_f32_16x16x32_bf16(af[m], bfr[n], acc[m][n], 0, 0, 0);
    __syncthreads();
  }
  // epilogue: C/D map col=lane&15, row=(lane>>4)*4+reg
#pragma unroll
  for (int m = 0; m < 4; ++m) {
#pragma unroll
    for (int r = 0; r < 4; ++r) {
      int gr = row0 + wr * 64 + m * 16 + quad * 4 + r;
      if (gr >= M) continue;
      float sv = 1.0f;
      int bofs = 0;
      if (WRITE_U) {
        sv = inv_s[gr];
        bofs = batch[gr] * 256;
      }
#pragma unroll
      for (int n = 0; n < 4; ++n) {
        int cc = wc * 64 + n * 16 + l15;
        float v = acc[m][n][r] + bias[cc];
        if (RELU) v = fmaxf(v, 0.f);
        if (WRITE_U) v = sv * (v + gh[bofs + cc]);
        out[(size_t)gr * 256 + cc] = f2bf(v);
      }
    }
  }
}

// ----------------------------- pool + final ---------------------------------

__global__ void pool_kernel(const unsigned short* __restrict__ h, const int* __restrict__ batch,
                            float* __restrict__ gmsum, float* __restrict__ cnt, int N, int chunk) {
  int start = blockIdx.x * chunk;
  int end = min(start + chunk, N);
  if (start >= end) return;
  int c = threadIdx.x;
  int g = batch[start];
  float acc = 0.0f;
  int run = 0;
  for (int n = start; n < end; ++n) {
    int bg = batch[n];
    if (bg != g) {
      atomicAdd(&gmsum[g * 256 + c], acc);
      if (c == 0) atomicAdd(&cnt[g], (float)run);
      acc = 0.0f;
      run = 0;
      g = bg;
    }
    acc += bf2f(h[(size_t)n * 256 + c]);
    run++;
  }
  atomicAdd(&gmsum[g * 256 + c], acc);
  if (c == 0) atomicAdd(&cnt[g], (float)run);
}

__global__ void final_kernel(const float* __restrict__ gmsum, const float* __restrict__ cnt,
                             const float* __restrict__ gh, const float* __restrict__ Wlin,
                             const float* __restrict__ blin, float* __restrict__ y,
                             float* __restrict__ gm_out, int G) {
  int g = blockIdx.x;
  int c = threadIdx.x;
  __shared__ float row[256];
  float v = gmsum[g * 256 + c] / fmaxf(cnt[g], 1.0f) + gh[g * 256 + c];
  gm_out[g * 256 + c] = v;
  row[c] = v;
  __syncthreads();
  if (c < 10) {
    float acc = blin[c];
    for (int k = 0; k < 256; ++k) acc += row[k] * Wlin[k * 10 + c];
    y[g * 10 + c] = acc;
  }
}

// ----------------------------- launch ----------------------------------------

extern "C" void kernel_launch(void* const* d_in, const int* in_sizes, int n_in,
                              void* d_out, int out_size, void* d_ws, size_t ws_size,
                              hipStream_t stream) {
  const float* x = (const float*)d_in[0];
  const int* ei = (const int*)d_in[1];
  const int* batch = (const int*)d_in[2];
  const float* gh = (const float*)d_in[3];
  const float* W0 = (const float*)d_in[4];
  const float* b0 = (const float*)d_in[5];
  const float* Ws = (const float*)d_in[6];
  const float* bs = (const float*)d_in[7];
  const float* Wlin = (const float*)d_in[8];
  const float* blin = (const float*)d_in[9];
  float* out = (float*)d_out;

  const int N = in_sizes[2];
  const int E = in_sizes[1] / 2;
  const int G = in_sizes[3] / 256;
  const int H = 256, L = 3, C = 10, F = 128;

  char* ws = (char*)d_ws;
  size_t off = 0;
  auto alloc = [&](size_t bytes) {
    void* p = ws + off;
    off += (bytes + 255) & ~(size_t)255;
    return p;
  };
  // NOTE: deg+cursor and cnt+gmsum are kept contiguous for merged memsets.
  size_t degspan = ((size_t)N * 4 + 255) & ~(size_t)255;
  size_t cntspan = ((size_t)G * 4 + 255) & ~(size_t)255;
  int* deg = (int*)alloc((size_t)N * 4);
  int* cursor = (int*)alloc((size_t)N * 4);
  float* cnt = (float*)alloc((size_t)G * 4);
  float* gmsum = (float*)alloc((size_t)G * H * 4);
  int* row_off = (int*)alloc((size_t)(N + 1) * 4);
  int* bsum = (int*)alloc(256 * 4);
  int* boff = (int*)alloc(256 * 4);
  int* col = (int*)alloc((size_t)E * 4);
  float* inv_s = (float*)alloc((size_t)N * 4);
  unsigned short* u_x = (unsigned short*)alloc((size_t)N * F * 2);   // s*x
  unsigned short* uA = (unsigned short*)alloc((size_t)N * H * 2);    // s*(h+res)
  unsigned short* aggA = (unsigned short*)alloc((size_t)N * H * 2);  // aggregate out / GEMM A
  unsigned short* hfin = (unsigned short*)alloc((size_t)N * H * 2);  // final h
  unsigned short* Wt0 = (unsigned short*)alloc((size_t)F * H * 2);   // [256][128]
  unsigned short* WtS = (unsigned short*)alloc((size_t)L * H * H * 2);

  const int* srcv = ei;
  const int* dstv = ei + E;

  hipMemsetAsync(deg, 0, degspan + (size_t)N * 4, stream);          // deg + cursor
  hipMemsetAsync(cnt, 0, cntspan + (size_t)G * H * 4, stream);     // cnt + gmsum

  int EB = (E + 255) / 256;
  int NB = (N + 255) / 256;
  count_deg_kernel<<<EB, 256, 0, stream>>>(dstv, deg, E);
  scan_partial_kernel<<<NB, 256, 0, stream>>>(deg, inv_s, bsum, N);
  scan_block_kernel<<<1, 256, 0, stream>>>(bsum, boff, row_off, NB, N);
  scan_final_kernel<<<NB, 256, 0, stream>>>(deg, boff, row_off, N);
  fill_csr_kernel<<<EB, 256, 0, stream>>>(srcv, dstv, row_off, cursor, col, E);

  prep_ux_kernel<<<(N * F + 255) / 256, 256, 0, stream>>>(x, inv_s, u_x, N * F);
  int TW = F * H + 3 * H * H;
  transpose_all_kernel<<<(TW + 255) / 256, 256, 0, stream>>>(W0, Ws, Wt0, WtS);

  int AGG_GRID = (N + 3) / 4;
  int GEMM_GRID = (N + 127) / 128;

  // layer 0: agg(u_x) -> GEMM K=128 (no relu) -> uA = s*(h0+res)
  aggregate_kernel<128><<<AGG_GRID, 256, 0, stream>>>(u_x, row_off, col, inv_s, aggA, N);
  gemm_kernel<128, false, true><<<GEMM_GRID, 512, 0, stream>>>(aggA, Wt0, b0, inv_s, batch, gh,
                                                               uA, N);
  // layers 1..2: agg(uA) -> GEMM relu -> uA
  for (int l = 0; l < 2; ++l) {
    aggregate_kernel<256><<<AGG_GRID, 256, 0, stream>>>(uA, row_off, col, inv_s, aggA, N);
    gemm_kernel<256, true, true><<<GEMM_GRID, 512, 0, stream>>>(
        aggA, WtS + (size_t)l * H * H, bs + (size_t)l * H, inv_s, batch, gh, uA, N);
  }
  // layer 3: agg(uA) -> GEMM relu -> h (bf16)
  aggregate_kernel<256><<<AGG_GRID, 256, 0, stream>>>(uA, row_off, col, inv_s, aggA, N);
  gemm_kernel<256, true, false><<<GEMM_GRID, 512, 0, stream>>>(
      aggA, WtS + (size_t)2 * H * H, bs + (size_t)2 * H, inv_s, batch, gh, hfin, N);

  int PB = 1024;
  int chunk = (N + PB - 1) / PB;
  pool_kernel<<<PB, 256, 0, stream>>>(hfin, batch, gmsum, cnt, N, chunk);
  final_kernel<<<G, 256, 0, stream>>>(gmsum, cnt, gh, Wlin, blin, out, out + (size_t)G * C, G);
}

// Round 4
// 511.772 us; speedup vs baseline: 1.4904x; 1.0038x over previous
//
#include <hip/hip_runtime.h>

// ---------------------------------------------------------------------------
// BlockGNN on MI355X, round 6:
//   - aggregate: 8 gathers issued via asm volatile global_load_dwordx4
//     (compiler cannot sink them; round-5 sched_barrier attempt was ignored,
//     VGPR stayed 32 => real depth ~2). One vmcnt(0) + sched_barrier(0) per
//     batch, AND-mask squash for invalid slots (no divergence).
//   - GEMM BM=128/512thr, launch-count reductions: unchanged from round 5.
// ---------------------------------------------------------------------------

typedef __bf16 bf16x8 __attribute__((ext_vector_type(8)));
typedef float f32x4 __attribute__((ext_vector_type(4)));
typedef unsigned int u32x4 __attribute__((ext_vector_type(4)));

__device__ inline float bf2f(unsigned short u) {
  union { unsigned int i; float f; } v;
  v.i = (unsigned int)u << 16;
  return v.f;
}
__device__ inline unsigned short f2bf(float f) {
  union { unsigned int i; float f; } v;
  v.f = f;
  unsigned int i = v.i;
  return (unsigned short)((i + 0x7fffu + ((i >> 16) & 1u)) >> 16);  // RNE
}
__device__ inline unsigned int pack2(float a, float b) {
  return (unsigned int)f2bf(a) | ((unsigned int)f2bf(b) << 16);
}
__device__ inline void acc8(float* acc, uint4 r) {
  unsigned int w[4] = {r.x, r.y, r.z, r.w};
#pragma unroll
  for (int q = 0; q < 4; ++q) {
    acc[2 * q] += bf2f((unsigned short)(w[q] & 0xffffu));
    acc[2 * q + 1] += bf2f((unsigned short)(w[q] >> 16));
  }
}
// masked accumulate of a u32x4 (4x2 bf16); msk==0 squashes to +0.0
__device__ inline void acc8m(float* acc, u32x4 r, unsigned msk) {
#pragma unroll
  for (int q = 0; q < 4; ++q) {
    unsigned w = r[q] & msk;
    acc[2 * q] += bf2f((unsigned short)(w & 0xffffu));
    acc[2 * q + 1] += bf2f((unsigned short)(w >> 16));
  }
}

// ----------------------------- CSR build -----------------------------------

__global__ void count_deg_kernel(const int* __restrict__ dst, int* __restrict__ deg, int E) {
  int e = blockIdx.x * blockDim.x + threadIdx.x;
  if (e < E) atomicAdd(&deg[dst[e]], 1);
}

// fused: per-block degree sums for the scan + inv_s = rsqrt(deg+1)
__global__ void scan_partial_kernel(const int* __restrict__ deg, float* __restrict__ inv_s,
                                    int* __restrict__ bsum, int N) {
  __shared__ int s[256];
  int i = blockIdx.x * 256 + threadIdx.x;
  int d = (i < N) ? deg[i] : 0;
  if (i < N) inv_s[i] = rsqrtf((float)(d + 1));  // +1 self loop
  s[threadIdx.x] = d;
  __syncthreads();
  for (int off = 128; off > 0; off >>= 1) {
    if (threadIdx.x < off) s[threadIdx.x] += s[threadIdx.x + off];
    __syncthreads();
  }
  if (threadIdx.x == 0) bsum[blockIdx.x] = s[0];
}

__global__ void scan_block_kernel(const int* __restrict__ bsum, int* __restrict__ boff,
                                  int* __restrict__ row_off, int NB, int N) {
  __shared__ int s[256];
  int v = (threadIdx.x < NB) ? bsum[threadIdx.x] : 0;
  s[threadIdx.x] = v;
  __syncthreads();
  for (int off = 1; off < 256; off <<= 1) {
    int t = (threadIdx.x >= off) ? s[threadIdx.x - off] : 0;
    __syncthreads();
    s[threadIdx.x] += t;
    __syncthreads();
  }
  boff[threadIdx.x] = s[threadIdx.x] - v;
  if (threadIdx.x == 255) row_off[N] = s[255];
}

__global__ void scan_final_kernel(const int* __restrict__ deg, const int* __restrict__ boff,
                                  int* __restrict__ row_off, int N) {
  __shared__ int s[256];
  int i = blockIdx.x * 256 + threadIdx.x;
  int v = (i < N) ? deg[i] : 0;
  s[threadIdx.x] = v;
  __syncthreads();
  for (int off = 1; off < 256; off <<= 1) {
    int t = (threadIdx.x >= off) ? s[threadIdx.x - off] : 0;
    __syncthreads();
    s[threadIdx.x] += t;
    __syncthreads();
  }
  if (i < N) row_off[i] = boff[blockIdx.x] + s[threadIdx.x] - v;
}

__global__ void fill_csr_kernel(const int* __restrict__ src, const int* __restrict__ dst,
                                const int* __restrict__ row_off, int* __restrict__ cursor,
                                int* __restrict__ col, int E) {
  int e = blockIdx.x * blockDim.x + threadIdx.x;
  if (e < E) {
    int d = dst[e];
    int pos = atomicAdd(&cursor[d], 1);
    col[row_off[d] + pos] = src[e];
  }
}

// ----------------------------- prep ----------------------------------------

// u_x[i][c] = bf16( inv_s[i] * x[i][c] ),  CH = 128
__global__ void prep_ux_kernel(const float* __restrict__ x, const float* __restrict__ inv_s,
                               unsigned short* __restrict__ u, int total) {
  int idx = blockIdx.x * 256 + threadIdx.x;
  if (idx < total) {
    int i = idx >> 7;
    u[idx] = f2bf(inv_s[i] * x[idx]);
  }
}

// single kernel transposing W0 [128][256] and 3x Ws [256][256] to bf16
__global__ void transpose_all_kernel(const float* __restrict__ W0, const float* __restrict__ Ws,
                                     unsigned short* __restrict__ Wt0,
                                     unsigned short* __restrict__ WtS) {
  const int FH = 128 * 256, HH = 256 * 256;
  int idx = blockIdx.x * 256 + threadIdx.x;
  if (idx < FH) {
    int k = idx >> 8, n = idx & 255;
    Wt0[n * 128 + k] = f2bf(W0[idx]);
  } else {
    int t = idx - FH;
    if (t < 3 * HH) {
      int l = t >> 16;
      int rem = t & 65535;
      int k = rem >> 8, n = rem & 255;
      WtS[l * HH + n * 256 + k] = f2bf(Ws[t]);
    }
  }
}

// ----------------------------- aggregate ------------------------------------
// out_i = bf16( s_i * ( u_i + sum_{j in in(i)} u_j ) )
// One wave per node; LPR lanes (16B each) per row; EPW edge-groups per wave.
// 8-deep gather batch issued as asm volatile global_load_dwordx4 so the
// compiler cannot sink the accumulates between the loads (true MLP depth 8,
// 128 B/lane in flight). Invalid slots clamp to the last edge (address always
// valid, L1-hit) and are squashed with an AND mask (bf16 0x0000 == +0.0).
template <int CH>
__global__ __launch_bounds__(256) void aggregate_kernel(
    const unsigned short* __restrict__ u, const int* __restrict__ row_off,
    const int* __restrict__ col, const float* __restrict__ inv_s,
    unsigned short* __restrict__ out, int N) {
  constexpr int LPR = CH / 8;    // lanes per row (each lane: 8 bf16 = 16B)
  constexpr int EPW = 64 / LPR;  // edge-groups in parallel per wave
  int wave = threadIdx.x >> 6;
  int lane = threadIdx.x & 63;
  int i = blockIdx.x * 4 + wave;
  if (i >= N) return;
  int sub = lane / LPR;
  int c = lane % LPR;
  int e0 = row_off[i], e1 = row_off[i + 1];
  int last = e1 - 1;
  const char* u8 = (const char*)u;
  float acc[8] = {};
  for (int e = e0 + sub; e < e1; e += 8 * EPW) {
    unsigned off[8];
    unsigned msk[8];
#pragma unroll
    for (int q = 0; q < 8; ++q) {
      int ee = e + q * EPW;
      bool v = ee < e1;
      int j = col[v ? ee : last];
      off[q] = (unsigned)j * (CH * 2) + c * 16;
      msk[q] = v ? 0xffffffffu : 0u;
    }
    u32x4 r[8];
#pragma unroll
    for (int q = 0; q < 8; ++q)
      asm volatile("global_load_dwordx4 %0, %1, %2"
                   : "=&v"(r[q])
                   : "v"(off[q]), "s"(u8));
    asm volatile("s_waitcnt vmcnt(0)" ::: "memory");
    __builtin_amdgcn_sched_barrier(0);  // rule #18: fence before register uses
#pragma unroll
    for (int q = 0; q < 8; ++q) acc8m(acc, r[q], msk[q]);
  }
#pragma unroll
  for (int k = 0; k < 8; ++k) {
    acc[k] += __shfl_down(acc[k], 32);
    if (EPW == 4) acc[k] += __shfl_down(acc[k], 16);
  }
  if (lane < LPR) {
    uint4 self = *(const uint4*)&u[(size_t)i * CH + c * 8];
    acc8(acc, self);
    float s = inv_s[i];
    uint4 o;
    o.x = pack2(s * acc[0], s * acc[1]);
    o.y = pack2(s * acc[2], s * acc[3]);
    o.z = pack2(s * acc[4], s * acc[5]);
    o.w = pack2(s * acc[6], s * acc[7]);
    *(uint4*)&out[(size_t)i * CH + c * 8] = o;
  }
}

// ----------------------------- MFMA GEMM ------------------------------------
// C[M,256] = A[M,K] @ W[K,256] (+bias, opt relu)
// BM=128, 8 waves (2 row-halves x 4 col-quarters), 512 threads.
// WRITE_U: out = bf16( inv_s[r] * (C + gh[batch[r]]) )   (next layer's u)
// else:    out = bf16( C )                               (final h)
template <int K, bool RELU, bool WRITE_U>
__global__ __launch_bounds__(512) void gemm_kernel(
    const unsigned short* __restrict__ A,   // [M][K] bf16
    const unsigned short* __restrict__ Bt,  // [256][K] bf16 (W transposed)
    const float* __restrict__ bias,         // [256]
    const float* __restrict__ inv_s, const int* __restrict__ batch,
    const float* __restrict__ gh,           // [G][256]
    unsigned short* __restrict__ out,       // [M][256] bf16
    int M) {
  constexpr int BK = 32;
  constexpr int LDT = 40;  // padded stride in ushorts: 80 B (16B-aligned, bank-friendly)
  __shared__ unsigned short As[128 * LDT];
  __shared__ unsigned short Bs[256 * LDT];
  int tid = threadIdx.x;
  int wave = tid >> 6, lane = tid & 63;
  int quad = lane >> 4, l15 = lane & 15;
  int wr = wave >> 2, wc = wave & 3;
  int row0 = blockIdx.x * 128;
  f32x4 acc[4][4];
#pragma unroll
  for (int m = 0; m < 4; ++m)
#pragma unroll
    for (int n = 0; n < 4; ++n) acc[m][n] = (f32x4){0.f, 0.f, 0.f, 0.f};

  for (int k0 = 0; k0 < K; k0 += BK) {
    {  // stage A: 128 rows x 32 k (one uint4 per thread)
      int r = tid >> 2, kq = tid & 3;
      int gr = row0 + r;
      uint4 v = make_uint4(0u, 0u, 0u, 0u);
      if (gr < M) v = *(const uint4*)&A[(size_t)gr * K + k0 + kq * 8];
      *(uint4*)&As[r * LDT + kq * 8] = v;
    }
#pragma unroll
    for (int p = 0; p < 2; ++p) {  // stage B: 256 rows x 32 k (two uint4 per thread)
      int n = (tid >> 2) + p * 128, kq = tid & 3;
      *(uint4*)&Bs[n * LDT + kq * 8] = *(const uint4*)&Bt[(size_t)n * K + k0 + kq * 8];
    }
    __syncthreads();
    bf16x8 af[4], bfr[4];
#pragma unroll
    for (int m = 0; m < 4; ++m)
      af[m] = __builtin_bit_cast(
          bf16x8, *(const uint4*)&As[(wr * 64 + m * 16 + l15) * LDT + quad * 8]);
#pragma unroll
    for (int n = 0; n < 4; ++n)
      bfr[n] = __builtin_bit_cast(
          bf16x8, *(const uint4*)&Bs[(wc * 64 + n * 16 + l15) * LDT + quad * 8]);
#pragma unroll
    for (int m = 0; m < 4; ++m)
#pragma unroll
      for (int n = 0; n < 4; ++n)
        acc[m][n] = __builtin_amdgcn_mfma_f32_16x16x32_bf16(af[m], bfr[n], acc[m][n], 0, 0, 0);
    __syncthreads();
  }
  // epilogue: C/D map col=lane&15, row=(lane>>4)*4+reg
#pragma unroll
  for (int m = 0; m < 4; ++m) {
#pragma unroll
    for (int r = 0; r < 4; ++r) {
      int gr = row0 + wr * 64 + m * 16 + quad * 4 + r;
      if (gr >= M) continue;
      float sv = 1.0f;
      int bofs = 0;
      if (WRITE_U) {
        sv = inv_s[gr];
        bofs = batch[gr] * 256;
      }
#pragma unroll
      for (int n = 0; n < 4; ++n) {
        int cc = wc * 64 + n * 16 + l15;
        float v = acc[m][n][r] + bias[cc];
        if (RELU) v = fmaxf(v, 0.f);
        if (WRITE_U) v = sv * (v + gh[bofs + cc]);
        out[(size_t)gr * 256 + cc] = f2bf(v);
      }
    }
  }
}

// ----------------------------- pool + final ---------------------------------

__global__ void pool_kernel(const unsigned short* __restrict__ h, const int* __restrict__ batch,
                            float* __restrict__ gmsum, float* __restrict__ cnt, int N, int chunk) {
  int start = blockIdx.x * chunk;
  int end = min(start + chunk, N);
  if (start >= end) return;
  int c = threadIdx.x;
  int g = batch[start];
  float acc = 0.0f;
  int run = 0;
  for (int n = start; n < end; ++n) {
    int bg = batch[n];
    if (bg != g) {
      atomicAdd(&gmsum[g * 256 + c], acc);
      if (c == 0) atomicAdd(&cnt[g], (float)run);
      acc = 0.0f;
      run = 0;
      g = bg;
    }
    acc += bf2f(h[(size_t)n * 256 + c]);
    run++;
  }
  atomicAdd(&gmsum[g * 256 + c], acc);
  if (c == 0) atomicAdd(&cnt[g], (float)run);
}

__global__ void final_kernel(const float* __restrict__ gmsum, const float* __restrict__ cnt,
                             const float* __restrict__ gh, const float* __restrict__ Wlin,
                             const float* __restrict__ blin, float* __restrict__ y,
                             float* __restrict__ gm_out, int G) {
  int g = blockIdx.x;
  int c = threadIdx.x;
  __shared__ float row[256];
  float v = gmsum[g * 256 + c] / fmaxf(cnt[g], 1.0f) + gh[g * 256 + c];
  gm_out[g * 256 + c] = v;
  row[c] = v;
  __syncthreads();
  if (c < 10) {
    float acc = blin[c];
    for (int k = 0; k < 256; ++k) acc += row[k] * Wlin[k * 10 + c];
    y[g * 10 + c] = acc;
  }
}

// ----------------------------- launch ----------------------------------------

extern "C" void kernel_launch(void* const* d_in, const int* in_sizes, int n_in,
                              void* d_out, int out_size, void* d_ws, size_t ws_size,
                              hipStream_t stream) {
  const float* x = (const float*)d_in[0];
  const int* ei = (const int*)d_in[1];
  const int* batch = (const int*)d_in[2];
  const float* gh = (const float*)d_in[3];
  const float* W0 = (const float*)d_in[4];
  const float* b0 = (const float*)d_in[5];
  const float* Ws = (const float*)d_in[6];
  const float* bs = (const float*)d_in[7];
  const float* Wlin = (const float*)d_in[8];
  const float* blin = (const float*)d_in[9];
  float* out = (float*)d_out;

  const int N = in_sizes[2];
  const int E = in_sizes[1] / 2;
  const int G = in_sizes[3] / 256;
  const int H = 256, L = 3, C = 10, F = 128;

  char* ws = (char*)d_ws;
  size_t off = 0;
  auto alloc = [&](size_t bytes) {
    void* p = ws + off;
    off += (bytes + 255) & ~(size_t)255;
    return p;
  };
  // NOTE: deg+cursor and cnt+gmsum are kept contiguous for merged memsets.
  size_t degspan = ((size_t)N * 4 + 255) & ~(size_t)255;
  size_t cntspan = ((size_t)G * 4 + 255) & ~(size_t)255;
  int* deg = (int*)alloc((size_t)N * 4);
  int* cursor = (int*)alloc((size_t)N * 4);
  float* cnt = (float*)alloc((size_t)G * 4);
  float* gmsum = (float*)alloc((size_t)G * H * 4);
  int* row_off = (int*)alloc((size_t)(N + 1) * 4);
  int* bsum = (int*)alloc(256 * 4);
  int* boff = (int*)alloc(256 * 4);
  int* col = (int*)alloc((size_t)E * 4);
  float* inv_s = (float*)alloc((size_t)N * 4);
  unsigned short* u_x = (unsigned short*)alloc((size_t)N * F * 2);   // s*x
  unsigned short* uA = (unsigned short*)alloc((size_t)N * H * 2);    // s*(h+res)
  unsigned short* aggA = (unsigned short*)alloc((size_t)N * H * 2);  // aggregate out / GEMM A
  unsigned short* hfin = (unsigned short*)alloc((size_t)N * H * 2);  // final h
  unsigned short* Wt0 = (unsigned short*)alloc((size_t)F * H * 2);   // [256][128]
  unsigned short* WtS = (unsigned short*)alloc((size_t)L * H * H * 2);

  const int* srcv = ei;
  const int* dstv = ei + E;

  hipMemsetAsync(deg, 0, degspan + (size_t)N * 4, stream);       // deg + cursor
  hipMemsetAsync(cnt, 0, cntspan + (size_t)G * H * 4, stream);   // cnt + gmsum

  int EB = (E + 255) / 256;
  int NB = (N + 255) / 256;
  count_deg_kernel<<<EB, 256, 0, stream>>>(dstv, deg, E);
  scan_partial_kernel<<<NB, 256, 0, stream>>>(deg, inv_s, bsum, N);
  scan_block_kernel<<<1, 256, 0, stream>>>(bsum, boff, row_off, NB, N);
  scan_final_kernel<<<NB, 256, 0, stream>>>(deg, boff, row_off, N);
  fill_csr_kernel<<<EB, 256, 0, stream>>>(srcv, dstv, row_off, cursor, col, E);

  prep_ux_kernel<<<(N * F + 255) / 256, 256, 0, stream>>>(x, inv_s, u_x, N * F);
  int TW = F * H + 3 * H * H;
  transpose_all_kernel<<<(TW + 255) / 256, 256, 0, stream>>>(W0, Ws, Wt0, WtS);

  int AGG_GRID = (N + 3) / 4;
  int GEMM_GRID = (N + 127) / 128;

  // layer 0: agg(u_x) -> GEMM K=128 (no relu) -> uA = s*(h0+res)
  aggregate_kernel<128><<<AGG_GRID, 256, 0, stream>>>(u_x, row_off, col, inv_s, aggA, N);
  gemm_kernel<128, false, true><<<GEMM_GRID, 512, 0, stream>>>(aggA, Wt0, b0, inv_s, batch, gh,
                                                               uA, N);
  // layers 1..2: agg(uA) -> GEMM relu -> uA
  for (int l = 0; l < 2; ++l) {
    aggregate_kernel<256><<<AGG_GRID, 256, 0, stream>>>(uA, row_off, col, inv_s, aggA, N);
    gemm_kernel<256, true, true><<<GEMM_GRID, 512, 0, stream>>>(
        aggA, WtS + (size_t)l * H * H, bs + (size_t)l * H, inv_s, batch, gh, uA, N);
  }
  // layer 3: agg(uA) -> GEMM relu -> h (bf16)
  aggregate_kernel<256><<<AGG_GRID, 256, 0, stream>>>(uA, row_off, col, inv_s, aggA, N);
  gemm_kernel<256, true, false><<<GEMM_GRID, 512, 0, stream>>>(
      aggA, WtS + (size_t)2 * H * H, bs + (size_t)2 * H, inv_s, batch, gh, hfin, N);

  int PB = 1024;
  int chunk = (N + PB - 1) / PB;
  pool_kernel<<<PB, 256, 0, stream>>>(hfin, batch, gmsum, cnt, N, chunk);
  final_kernel<<<G, 256, 0, stream>>>(gmsum, cnt, gh, Wlin, blin, out, out + (size_t)G * C, G);
}